// Round 6
// baseline (114.814 us; speedup 1.0000x reference)
//
#include <hip/hip_runtime.h>
#include <math.h>

#define N_ROWS 262144
#define D_IN 64
#define RFF 256
#define NTILES (N_ROWS / 16)                 // 16384
#define GRID_BIG 1024
#define TILES_PER_BLOCK (NTILES / GRID_BIG)  // 16
#define TILES_PER_WAVE (TILES_PER_BLOCK / 4) // 4

// d_out layout (floats): predictions[N*3] | AW[N*3] | reg_loss | alpha[256]
#define OFF_PRED 0
#define OFF_AW (N_ROWS * 3)
#define OFF_REG (2 * N_ROWS * 3)
#define OFF_ALPHA (2 * N_ROWS * 3 + 1)

// ws layout: U f32[512] | BtP u32[256*3] (packed bf16: lo=cos-coef, hi=sin-coef)
#define WS_B 512

typedef _Float16 f16x8 __attribute__((ext_vector_type(8)));
typedef float f32x4 __attribute__((ext_vector_type(4)));

__device__ __forceinline__ f32x4 mfma16(f16x8 a, f16x8 b, f32x4 c) {
    return __builtin_amdgcn_mfma_f32_16x16x32_f16(a, b, c, 0, 0, 0);
}

__device__ __forceinline__ unsigned short f32_to_bf16_rne(float x) {
    unsigned int u = __float_as_uint(x);
    unsigned int r = u + 0x7fffu + ((u >> 16) & 1u);
    return (unsigned short)(r >> 16);
}

// Stage W (64x256 f32) into LDS as f16 B-fragments.
// B-frag layout (v_mfma_f32_16x16x32_f16): lane l, elem i ->
//   k = kh*32 + 8*(l>>4) + i, col = ct*16 + (l&15).  slot = (ct*2+kh)*64 + l.
__device__ __forceinline__ void prep_W(const float* __restrict__ W, f16x8* Bf, int t) {
#pragma unroll
    for (int q = 0; q < 8; ++q) {
        const int s = t + 256 * q;
        const int lane = s & 63;
        const int kh = (s >> 6) & 1;
        const int ct = s >> 7;
        const int k0 = kh * 32 + 8 * (lane >> 4);
        const int col = ct * 16 + (lane & 15);
        f16x8 v;
#pragma unroll
        for (int i = 0; i < 8; ++i) v[i] = (_Float16)W[(k0 + i) * RFF + col];
        Bf[(ct * 2 + kh) * 64 + lane] = v;
    }
}

// T14 split staging: issue coalesced global->reg loads early ...
__device__ __forceinline__ void load_tile(const float* __restrict__ Z, int n0, int l,
                                          float4* pf) {
#pragma unroll
    for (int rep = 0; rep < 4; ++rep) {
        const int row = (rep >> 1) * 8 + (l >> 3);
        const int col = (rep & 1) * 32 + (l & 7) * 4;
        pf[rep] = *(const float4*)(Z + (size_t)(n0 + row) * D_IN + col);
    }
}

// ... and write regs->LDS late (vmcnt wait lands here, under prior compute).
__device__ __forceinline__ void write_tile(float (*Zw)[68], int l, const float4* pf) {
#pragma unroll
    for (int rep = 0; rep < 4; ++rep) {
        const int row = (rep >> 1) * 8 + (l >> 3);
        const int col = (rep & 1) * 32 + (l & 7) * 4;
        *(float4*)&Zw[row][col] = pf[rep];
    }
    asm volatile("s_waitcnt lgkmcnt(0)" ::: "memory");
}

// Read this lane's A-fragments (f16 hi + f16 residual lo) from the staged tile.
__device__ __forceinline__ void frags_from_lds(const float (*Zw)[68], int lr, int lh,
                                               f16x8& ah0, f16x8& al0, f16x8& ah1, f16x8& al1) {
    const float* zr = &Zw[lr][lh * 8];
    float z[16];
    *(float4*)&z[0] = *(const float4*)(zr);
    *(float4*)&z[4] = *(const float4*)(zr + 4);
    *(float4*)&z[8] = *(const float4*)(zr + 32);
    *(float4*)&z[12] = *(const float4*)(zr + 36);
#pragma unroll
    for (int i = 0; i < 8; ++i) {
        _Float16 h0 = (_Float16)z[i];
        ah0[i] = h0;
        al0[i] = (_Float16)(z[i] - (float)h0);
        _Float16 h1 = (_Float16)z[8 + i];
        ah1[i] = h1;
        al1[i] = (_Float16)(z[8 + i] - (float)h1);
    }
}

// ---------------- Pass 1: U[f] = sum_n Q[n,f] via MFMA ----------------
__global__ __launch_bounds__(256, 3) void k_pass1(const float* __restrict__ Z,
                                                  const float* __restrict__ W,
                                                  float* __restrict__ U) {
    __shared__ f16x8 Bf[2048];       // 32 KB
    __shared__ float Zs[4][16][68];  // 17.4 KB
    __shared__ float Ured[512];
    const int t = threadIdx.x;
    prep_W(W, Bf, t);
    Ured[t] = 0.f;
    Ured[t + 256] = 0.f;
    __syncthreads();

    const int wv = t >> 6, l = t & 63, lr = l & 15, lh = l >> 4;
    float accC[16], accS[16];
#pragma unroll
    for (int c = 0; c < 16; ++c) { accC[c] = 0.f; accS[c] = 0.f; }

    const int tile0 = blockIdx.x * TILES_PER_BLOCK + wv * TILES_PER_WAVE;
    float4 pf[4];
    load_tile(Z, tile0 * 16, l, pf);

    for (int tt = 0; tt < TILES_PER_WAVE; ++tt) {
        write_tile(Zs[wv], l, pf);
        f16x8 ah0, al0, ah1, al1;
        frags_from_lds(Zs[wv], lr, lh, ah0, al0, ah1, al1);
        if (tt + 1 < TILES_PER_WAVE) load_tile(Z, (tile0 + tt + 1) * 16, l, pf);
        f32x4 acc[16];
#pragma unroll
        for (int ct = 0; ct < 16; ++ct) acc[ct] = (f32x4){0.f, 0.f, 0.f, 0.f};
#pragma unroll
        for (int ct = 0; ct < 16; ++ct) {
            f16x8 b0 = Bf[(ct * 2 + 0) * 64 + l];
            f16x8 b1 = Bf[(ct * 2 + 1) * 64 + l];
            acc[ct] = mfma16(ah0, b0, acc[ct]);
            acc[ct] = mfma16(ah1, b1, acc[ct]);
            acc[ct] = mfma16(al0, b0, acc[ct]);
            acc[ct] = mfma16(al1, b1, acc[ct]);
        }
#pragma unroll
        for (int ct = 0; ct < 16; ++ct) {
#pragma unroll
            for (int r = 0; r < 4; ++r) {
                float sn, cs;
                __sincosf(acc[ct][r], &sn, &cs);
                accC[ct] += cs;
                accS[ct] += sn;
            }
        }
    }
#pragma unroll
    for (int ct = 0; ct < 16; ++ct) {
        accC[ct] += __shfl_xor(accC[ct], 16);
        accC[ct] += __shfl_xor(accC[ct], 32);
        accS[ct] += __shfl_xor(accS[ct], 16);
        accS[ct] += __shfl_xor(accS[ct], 32);
    }
    if (l < 16) {
#pragma unroll
        for (int ct = 0; ct < 16; ++ct) {
            atomicAdd(&Ured[ct * 16 + l], accC[ct] * 0.0625f);
            atomicAdd(&Ured[256 + ct * 16 + l], accS[ct] * 0.0625f);
        }
    }
    __syncthreads();
    atomicAdd(&U[t], Ured[t]);
    atomicAdd(&U[t + 256], Ured[t + 256]);
}

// ------------- Tiny kernel: alpha, packed B coefs, reg_loss -------------
__global__ __launch_bounds__(256) void k_alpha(const float* __restrict__ U,
                                               const float* __restrict__ A,
                                               float* __restrict__ ws,
                                               float* __restrict__ out) {
    __shared__ float sm[256];
    __shared__ double gred[256];
    __shared__ double G6[6];
    const int k = threadIdx.x;

    const float am0 = (A[0] + A[1] + A[2]) * (1.0f / 3.0f);
    const float am1 = (A[3] + A[4] + A[5]) * (1.0f / 3.0f);
    float score = (am0 * U[2 * k] + am1 * U[2 * k + 1]) * (1.0f / (float)N_ROWS);
    float x = score * (1.0f / 1.6f);

    sm[k] = x;
    __syncthreads();
    for (int s = 128; s > 0; s >>= 1) {
        if (k < s) sm[k] = fmaxf(sm[k], sm[k + s]);
        __syncthreads();
    }
    float mx = sm[0];
    __syncthreads();
    float e = __expf(x - mx);
    sm[k] = e;
    __syncthreads();
    for (int s = 128; s > 0; s >>= 1) {
        if (k < s) sm[k] += sm[k + s];
        __syncthreads();
    }
    float al = e / sm[0];
    out[OFF_ALPHA + k] = al;
    sm[k] = al;
    __syncthreads();

    {
        const float ac = 0.0625f * sm[k >> 1];
        const float as = 0.0625f * sm[128 + (k >> 1)];
        unsigned int* BtP = (unsigned int*)(ws + WS_B);
#pragma unroll
        for (int j = 0; j < 3; ++j) {
            float bc = ac * A[k * 3 + j];
            float bs = as * A[(256 + k) * 3 + j];
            unsigned int ulo = f32_to_bf16_rne(bc);
            unsigned int uhi = f32_to_bf16_rne(bs);
            BtP[k * 3 + j] = ulo | (uhi << 16);
        }
    }

    // nuclear norm of A (512x3): G = A^T A in double, closed-form eigs
    double af[2][3];
#pragma unroll
    for (int t2 = 0; t2 < 2; ++t2)
#pragma unroll
        for (int j = 0; j < 3; ++j) af[t2][j] = (double)A[(k + t2 * 256) * 3 + j];
    const int ei[6] = {0, 0, 0, 1, 1, 2};
    const int ej[6] = {0, 1, 2, 1, 2, 2};
    for (int eidx = 0; eidx < 6; ++eidx) {
        double p = af[0][ei[eidx]] * af[0][ej[eidx]] + af[1][ei[eidx]] * af[1][ej[eidx]];
        gred[k] = p;
        __syncthreads();
        for (int s = 128; s > 0; s >>= 1) {
            if (k < s) gred[k] += gred[k + s];
            __syncthreads();
        }
        if (k == 0) G6[eidx] = gred[0];
        __syncthreads();
    }
    if (k == 0) {
        double g00 = G6[0], g01 = G6[1], g02 = G6[2], g11 = G6[3], g12 = G6[4], g22 = G6[5];
        double q = (g00 + g11 + g22) / 3.0;
        double p1 = g01 * g01 + g02 * g02 + g12 * g12;
        double p2 = (g00 - q) * (g00 - q) + (g11 - q) * (g11 - q) + (g22 - q) * (g22 - q) + 2.0 * p1;
        double nuc;
        if (p2 < 1e-300) {
            nuc = 3.0 * sqrt(fmax(q, 0.0));
        } else {
            double p = sqrt(p2 / 6.0);
            double b00 = (g00 - q) / p, b11 = (g11 - q) / p, b22 = (g22 - q) / p;
            double b01 = g01 / p, b02 = g02 / p, b12 = g12 / p;
            double detB = b00 * (b11 * b22 - b12 * b12) - b01 * (b01 * b22 - b12 * b02) +
                          b02 * (b01 * b12 - b11 * b02);
            double rr = detB / 2.0;
            rr = fmin(1.0, fmax(-1.0, rr));
            double phi = acos(rr) / 3.0;
            double e1 = q + 2.0 * p * cos(phi);
            double e3 = q + 2.0 * p * cos(phi + 2.0943951023931953);
            double e2 = 3.0 * q - e1 - e3;
            nuc = sqrt(fmax(e1, 0.0)) + sqrt(fmax(e2, 0.0)) + sqrt(fmax(e3, 0.0));
        }
        out[OFF_REG] = (float)(0.01 * nuc);
    }
}

// ---------------- Pass 2: predictions + AW via MFMA ----------------
__global__ __launch_bounds__(256, 3) void k_pass2(const float* __restrict__ Z,
                                                  const float* __restrict__ W,
                                                  const float* __restrict__ ws,
                                                  float* __restrict__ out) {
    __shared__ f16x8 Bf[2048];        // 32 KB
    __shared__ float Zs[4][16][68];   // 17.4 KB
    __shared__ unsigned int BtP[768]; // 3 KB packed coefs
    const int t = threadIdx.x;
    prep_W(W, Bf, t);
    {
        const unsigned int* src = (const unsigned int*)(ws + WS_B);
        BtP[t] = src[t];
        BtP[t + 256] = src[t + 256];
        BtP[t + 512] = src[t + 512];
    }
    __syncthreads();

    const int wv = t >> 6, l = t & 63, lr = l & 15, lh = l >> 4;

    const int tile0 = blockIdx.x * TILES_PER_BLOCK + wv * TILES_PER_WAVE;
    float4 pf[4];
    load_tile(Z, tile0 * 16, l, pf);

    for (int tt = 0; tt < TILES_PER_WAVE; ++tt) {
        const int n0 = (tile0 + tt) * 16;
        write_tile(Zs[wv], l, pf);
        f16x8 ah0, al0, ah1, al1;
        frags_from_lds(Zs[wv], lr, lh, ah0, al0, ah1, al1);
        if (tt + 1 < TILES_PER_WAVE) load_tile(Z, (tile0 + tt + 1) * 16, l, pf);
        f32x4 acc[16];
#pragma unroll
        for (int ct = 0; ct < 16; ++ct) acc[ct] = (f32x4){0.f, 0.f, 0.f, 0.f};
#pragma unroll
        for (int ct = 0; ct < 16; ++ct) {
            f16x8 b0 = Bf[(ct * 2 + 0) * 64 + l];
            f16x8 b1 = Bf[(ct * 2 + 1) * 64 + l];
            acc[ct] = mfma16(ah0, b0, acc[ct]);
            acc[ct] = mfma16(ah1, b1, acc[ct]);
            acc[ct] = mfma16(al0, b0, acc[ct]);
            acc[ct] = mfma16(al1, b1, acc[ct]);
        }
        float pa[4][3];
#pragma unroll
        for (int r = 0; r < 4; ++r) { pa[r][0] = 0.f; pa[r][1] = 0.f; pa[r][2] = 0.f; }
#pragma unroll
        for (int ct = 0; ct < 16; ++ct) {
            const int f = ct * 16 + lr;
            unsigned int u0 = BtP[f * 3 + 0], u1 = BtP[f * 3 + 1], u2 = BtP[f * 3 + 2];
            float bc0 = __uint_as_float(u0 << 16), bs0 = __uint_as_float(u0 & 0xffff0000u);
            float bc1 = __uint_as_float(u1 << 16), bs1 = __uint_as_float(u1 & 0xffff0000u);
            float bc2 = __uint_as_float(u2 << 16), bs2 = __uint_as_float(u2 & 0xffff0000u);
#pragma unroll
            for (int r = 0; r < 4; ++r) {
                float sn, cs;
                __sincosf(acc[ct][r], &sn, &cs);
                pa[r][0] = __builtin_fmaf(cs, bc0, __builtin_fmaf(sn, bs0, pa[r][0]));
                pa[r][1] = __builtin_fmaf(cs, bc1, __builtin_fmaf(sn, bs1, pa[r][1]));
                pa[r][2] = __builtin_fmaf(cs, bc2, __builtin_fmaf(sn, bs2, pa[r][2]));
            }
        }
#pragma unroll
        for (int r = 0; r < 4; ++r)
#pragma unroll
            for (int j = 0; j < 3; ++j) {
                pa[r][j] += __shfl_xor(pa[r][j], 1);
                pa[r][j] += __shfl_xor(pa[r][j], 2);
                pa[r][j] += __shfl_xor(pa[r][j], 4);
                pa[r][j] += __shfl_xor(pa[r][j], 8);
            }
        float q0 = 0.f, q1 = 0.f, q2 = 0.f;
#pragma unroll
        for (int r = 0; r < 4; ++r)
            if (lr == r) { q0 = pa[r][0]; q1 = pa[r][1]; q2 = pa[r][2]; }
        if (lr < 4) {
            const size_t n = (size_t)n0 + 4 * lh + lr;
            out[OFF_PRED + n * 3 + 0] = q0;
            out[OFF_PRED + n * 3 + 1] = q1;
            out[OFF_PRED + n * 3 + 2] = q2;
            float x0 = q0 * 0.0625f, x1 = q1 * 0.0625f, x2 = q2 * 0.0625f;
            float m = fmaxf(x0, fmaxf(x1, x2));
            float e0 = __expf(x0 - m), e1 = __expf(x1 - m), e2 = __expf(x2 - m);
            float inv = 1.0f / (e0 + e1 + e2);
            out[OFF_AW + n * 3 + 0] = e0 * inv;
            out[OFF_AW + n * 3 + 1] = e1 * inv;
            out[OFF_AW + n * 3 + 2] = e2 * inv;
        }
    }
}

extern "C" void kernel_launch(void* const* d_in, const int* in_sizes, int n_in,
                              void* d_out, int out_size, void* d_ws, size_t ws_size,
                              hipStream_t stream) {
    const float* Z = (const float*)d_in[0];
    const float* W = (const float*)d_in[1];
    const float* A = (const float*)d_in[2];
    float* out = (float*)d_out;
    float* ws = (float*)d_ws;

    (void)hipMemsetAsync(ws, 0, 512 * sizeof(float), stream);
    hipLaunchKernelGGL(k_pass1, dim3(GRID_BIG), dim3(256), 0, stream, Z, W, ws);
    hipLaunchKernelGGL(k_alpha, dim3(1), dim3(256), 0, stream, ws, A, ws, out);
    hipLaunchKernelGGL(k_pass2, dim3(GRID_BIG), dim3(256), 0, stream, Z, W, ws, out);
}

// Round 7
// 95.983 us; speedup vs baseline: 1.1962x; 1.1962x over previous
//
#include <hip/hip_runtime.h>
#include <math.h>

#define N_ROWS 262144
#define D_IN 64
#define RFF 256
#define NTILES (N_ROWS / 16)                 // 16384
#define GRID_BIG 512
#define TILES_PER_BLOCK (NTILES / GRID_BIG)  // 32
#define TILES_PER_WAVE (TILES_PER_BLOCK / 4) // 8

// d_out layout (floats): predictions[N*3] | AW[N*3] | reg_loss | alpha[256]
#define OFF_PRED 0
#define OFF_AW (N_ROWS * 3)
#define OFF_REG (2 * N_ROWS * 3)
#define OFF_ALPHA (2 * N_ROWS * 3 + 1)

// ws layout: U f32[512] | BtP u32[256*3] (packed bf16: lo=cos-coef, hi=sin-coef)
#define WS_B 512

typedef _Float16 f16x8 __attribute__((ext_vector_type(8)));
typedef float f32x4 __attribute__((ext_vector_type(4)));

__device__ __forceinline__ f32x4 mfma16(f16x8 a, f16x8 b, f32x4 c) {
    return __builtin_amdgcn_mfma_f32_16x16x32_f16(a, b, c, 0, 0, 0);
}

__device__ __forceinline__ unsigned short f32_to_bf16_rne(float x) {
    unsigned int u = __float_as_uint(x);
    unsigned int r = u + 0x7fffu + ((u >> 16) & 1u);
    return (unsigned short)(r >> 16);
}

// async global->LDS, 16B per lane; LDS dest = base + lane*16 (wave-linear)
__device__ __forceinline__ void gload_lds16(const float* g, float* lds) {
    __builtin_amdgcn_global_load_lds(
        (const __attribute__((address_space(1))) unsigned int*)g,
        (__attribute__((address_space(3))) unsigned int*)(lds), 16, 0, 0);
}

// Stage W (64x256 f32) into LDS as f16 B-fragments.
// B-frag layout (v_mfma_f32_16x16x32_f16): lane l, elem i ->
//   k = kh*32 + 8*(l>>4) + i, col = ct*16 + (l&15).  slot = (ct*2+kh)*64 + l.
__device__ __forceinline__ void prep_W(const float* __restrict__ W, f16x8* Bf, int t) {
#pragma unroll
    for (int q = 0; q < 8; ++q) {
        const int s = t + 256 * q;
        const int lane = s & 63;
        const int kh = (s >> 6) & 1;
        const int ct = s >> 7;
        const int k0 = kh * 32 + 8 * (lane >> 4);
        const int col = ct * 16 + (lane & 15);
        f16x8 v;
#pragma unroll
        for (int i = 0; i < 8; ++i) v[i] = (_Float16)W[(k0 + i) * RFF + col];
        Bf[(ct * 2 + kh) * 64 + lane] = v;
    }
}

// Issue the 4 DMA ops for one 16x64 tile into this wave's buffer.
// Issue m covers rows m*4..m*4+3 (contiguous 1KB of Z). LDS granule (row, c)
// holds global granule (row, c ^ (row&7))  [XOR swizzle, involution].
__device__ __forceinline__ void stage_dma(const float* __restrict__ Z, int n0, int l,
                                          float* ldsbase) {
#pragma unroll
    for (int m = 0; m < 4; ++m) {
        const int row = m * 4 + (l >> 4);
        const int gc = (l & 15) ^ (row & 7);
        gload_lds16(Z + (size_t)(n0 + row) * D_IN + gc * 4, ldsbase + m * 256);
    }
}

// Read this lane's A-fragments (f16 hi + f16 residual lo) from the swizzled tile.
__device__ __forceinline__ void frags_from_lds(const float* bb, int lr, int lh,
                                               f16x8& ah0, f16x8& al0, f16x8& ah1, f16x8& al1) {
    const int s4 = lr & 7;
    const float* rp = bb + lr * 64;
    float z[16];
    *(float4*)&z[0]  = *(const float4*)(rp + (((lh * 2 + 0) ^ s4) << 2));
    *(float4*)&z[4]  = *(const float4*)(rp + (((lh * 2 + 1) ^ s4) << 2));
    *(float4*)&z[8]  = *(const float4*)(rp + (((lh * 2 + 8) ^ s4) << 2));
    *(float4*)&z[12] = *(const float4*)(rp + (((lh * 2 + 9) ^ s4) << 2));
#pragma unroll
    for (int i = 0; i < 8; ++i) {
        _Float16 h0 = (_Float16)z[i];
        ah0[i] = h0;
        al0[i] = (_Float16)(z[i] - (float)h0);
        _Float16 h1 = (_Float16)z[8 + i];
        ah1[i] = h1;
        al1[i] = (_Float16)(z[8 + i] - (float)h1);
    }
}

#define WAITVM4() do { asm volatile("s_waitcnt vmcnt(4)" ::: "memory"); \
                       __builtin_amdgcn_sched_barrier(0); } while (0)
#define WAITVM0() do { asm volatile("s_waitcnt vmcnt(0)" ::: "memory"); \
                       __builtin_amdgcn_sched_barrier(0); } while (0)

// ---------------- Pass 1: U[f] = sum_n Q[n,f] via MFMA ----------------
__global__ __launch_bounds__(256, 2) void k_pass1(const float* __restrict__ Z,
                                                  const float* __restrict__ W,
                                                  float* __restrict__ U) {
    __shared__ f16x8 Bf[2048];          // 32 KB
    __shared__ float Zs[4][2][1024];    // 32 KB: per-wave double buffer
    __shared__ float Ured[512];
    const int t = threadIdx.x;
    prep_W(W, Bf, t);
    Ured[t] = 0.f;
    Ured[t + 256] = 0.f;
    __syncthreads();

    const int wv = t >> 6, l = t & 63, lr = l & 15, lh = l >> 4;
    float accC[16], accS[16];
#pragma unroll
    for (int c = 0; c < 16; ++c) { accC[c] = 0.f; accS[c] = 0.f; }

    const int tile0 = blockIdx.x * TILES_PER_BLOCK + wv * TILES_PER_WAVE;
    stage_dma(Z, tile0 * 16, l, &Zs[wv][0][0]);

    for (int tt = 0; tt < TILES_PER_WAVE; ++tt) {
        if (tt + 1 < TILES_PER_WAVE) {
            stage_dma(Z, (tile0 + tt + 1) * 16, l, &Zs[wv][(tt + 1) & 1][0]);
            WAITVM4();
        } else {
            WAITVM0();
        }
        f16x8 ah0, al0, ah1, al1;
        frags_from_lds(&Zs[wv][tt & 1][0], lr, lh, ah0, al0, ah1, al1);
        f32x4 acc[16];
#pragma unroll
        for (int ct = 0; ct < 16; ++ct) acc[ct] = (f32x4){0.f, 0.f, 0.f, 0.f};
#pragma unroll
        for (int ct = 0; ct < 16; ++ct) {
            f16x8 b0 = Bf[(ct * 2 + 0) * 64 + l];
            f16x8 b1 = Bf[(ct * 2 + 1) * 64 + l];
            acc[ct] = mfma16(ah0, b0, acc[ct]);
            acc[ct] = mfma16(ah1, b1, acc[ct]);
            acc[ct] = mfma16(al0, b0, acc[ct]);
            acc[ct] = mfma16(al1, b1, acc[ct]);
        }
#pragma unroll
        for (int ct = 0; ct < 16; ++ct) {
#pragma unroll
            for (int r = 0; r < 4; ++r) {
                float sn, cs;
                __sincosf(acc[ct][r], &sn, &cs);
                accC[ct] += cs;
                accS[ct] += sn;
            }
        }
    }
#pragma unroll
    for (int ct = 0; ct < 16; ++ct) {
        accC[ct] += __shfl_xor(accC[ct], 16);
        accC[ct] += __shfl_xor(accC[ct], 32);
        accS[ct] += __shfl_xor(accS[ct], 16);
        accS[ct] += __shfl_xor(accS[ct], 32);
    }
    if (l < 16) {
#pragma unroll
        for (int ct = 0; ct < 16; ++ct) {
            atomicAdd(&Ured[ct * 16 + l], accC[ct] * 0.0625f);
            atomicAdd(&Ured[256 + ct * 16 + l], accS[ct] * 0.0625f);
        }
    }
    __syncthreads();
    atomicAdd(&U[t], Ured[t]);
    atomicAdd(&U[t + 256], Ured[t + 256]);
}

// ------------- Tiny kernel: alpha, packed B coefs, reg_loss -------------
__global__ __launch_bounds__(256) void k_alpha(const float* __restrict__ U,
                                               const float* __restrict__ A,
                                               float* __restrict__ ws,
                                               float* __restrict__ out) {
    __shared__ float sm[256];
    __shared__ double gred[256];
    __shared__ double G6[6];
    const int k = threadIdx.x;

    const float am0 = (A[0] + A[1] + A[2]) * (1.0f / 3.0f);
    const float am1 = (A[3] + A[4] + A[5]) * (1.0f / 3.0f);
    float score = (am0 * U[2 * k] + am1 * U[2 * k + 1]) * (1.0f / (float)N_ROWS);
    float x = score * (1.0f / 1.6f);

    sm[k] = x;
    __syncthreads();
    for (int s = 128; s > 0; s >>= 1) {
        if (k < s) sm[k] = fmaxf(sm[k], sm[k + s]);
        __syncthreads();
    }
    float mx = sm[0];
    __syncthreads();
    float e = __expf(x - mx);
    sm[k] = e;
    __syncthreads();
    for (int s = 128; s > 0; s >>= 1) {
        if (k < s) sm[k] += sm[k + s];
        __syncthreads();
    }
    float al = e / sm[0];
    out[OFF_ALPHA + k] = al;
    sm[k] = al;
    __syncthreads();

    {
        const float ac = 0.0625f * sm[k >> 1];
        const float as = 0.0625f * sm[128 + (k >> 1)];
        unsigned int* BtP = (unsigned int*)(ws + WS_B);
#pragma unroll
        for (int j = 0; j < 3; ++j) {
            float bc = ac * A[k * 3 + j];
            float bs = as * A[(256 + k) * 3 + j];
            unsigned int ulo = f32_to_bf16_rne(bc);
            unsigned int uhi = f32_to_bf16_rne(bs);
            BtP[k * 3 + j] = ulo | (uhi << 16);
        }
    }

    // nuclear norm of A (512x3): G = A^T A in double, closed-form eigs
    double af[2][3];
#pragma unroll
    for (int t2 = 0; t2 < 2; ++t2)
#pragma unroll
        for (int j = 0; j < 3; ++j) af[t2][j] = (double)A[(k + t2 * 256) * 3 + j];
    const int ei[6] = {0, 0, 0, 1, 1, 2};
    const int ej[6] = {0, 1, 2, 1, 2, 2};
    for (int eidx = 0; eidx < 6; ++eidx) {
        double p = af[0][ei[eidx]] * af[0][ej[eidx]] + af[1][ei[eidx]] * af[1][ej[eidx]];
        gred[k] = p;
        __syncthreads();
        for (int s = 128; s > 0; s >>= 1) {
            if (k < s) gred[k] += gred[k + s];
            __syncthreads();
        }
        if (k == 0) G6[eidx] = gred[0];
        __syncthreads();
    }
    if (k == 0) {
        double g00 = G6[0], g01 = G6[1], g02 = G6[2], g11 = G6[3], g12 = G6[4], g22 = G6[5];
        double q = (g00 + g11 + g22) / 3.0;
        double p1 = g01 * g01 + g02 * g02 + g12 * g12;
        double p2 = (g00 - q) * (g00 - q) + (g11 - q) * (g11 - q) + (g22 - q) * (g22 - q) + 2.0 * p1;
        double nuc;
        if (p2 < 1e-300) {
            nuc = 3.0 * sqrt(fmax(q, 0.0));
        } else {
            double p = sqrt(p2 / 6.0);
            double b00 = (g00 - q) / p, b11 = (g11 - q) / p, b22 = (g22 - q) / p;
            double b01 = g01 / p, b02 = g02 / p, b12 = g12 / p;
            double detB = b00 * (b11 * b22 - b12 * b12) - b01 * (b01 * b22 - b12 * b02) +
                          b02 * (b01 * b12 - b11 * b02);
            double rr = detB / 2.0;
            rr = fmin(1.0, fmax(-1.0, rr));
            double phi = acos(rr) / 3.0;
            double e1 = q + 2.0 * p * cos(phi);
            double e3 = q + 2.0 * p * cos(phi + 2.0943951023931953);
            double e2 = 3.0 * q - e1 - e3;
            nuc = sqrt(fmax(e1, 0.0)) + sqrt(fmax(e2, 0.0)) + sqrt(fmax(e3, 0.0));
        }
        out[OFF_REG] = (float)(0.01 * nuc);
    }
}

// ---------------- Pass 2: predictions + AW via MFMA ----------------
__global__ __launch_bounds__(256, 2) void k_pass2(const float* __restrict__ Z,
                                                  const float* __restrict__ W,
                                                  const float* __restrict__ ws,
                                                  float* __restrict__ out) {
    __shared__ f16x8 Bf[2048];        // 32 KB
    __shared__ float Zs[4][2][1024];  // 32 KB
    __shared__ unsigned int BtP[768]; // 3 KB packed coefs
    const int t = threadIdx.x;
    prep_W(W, Bf, t);
    {
        const unsigned int* src = (const unsigned int*)(ws + WS_B);
        BtP[t] = src[t];
        BtP[t + 256] = src[t + 256];
        BtP[t + 512] = src[t + 512];
    }
    __syncthreads();

    const int wv = t >> 6, l = t & 63, lr = l & 15, lh = l >> 4;

    const int tile0 = blockIdx.x * TILES_PER_BLOCK + wv * TILES_PER_WAVE;
    stage_dma(Z, tile0 * 16, l, &Zs[wv][0][0]);

    for (int tt = 0; tt < TILES_PER_WAVE; ++tt) {
        const int n0 = (tile0 + tt) * 16;
        if (tt + 1 < TILES_PER_WAVE) {
            stage_dma(Z, (tile0 + tt + 1) * 16, l, &Zs[wv][(tt + 1) & 1][0]);
            WAITVM4();
        } else {
            WAITVM0();
        }
        f16x8 ah0, al0, ah1, al1;
        frags_from_lds(&Zs[wv][tt & 1][0], lr, lh, ah0, al0, ah1, al1);
        f32x4 acc[16];
#pragma unroll
        for (int ct = 0; ct < 16; ++ct) acc[ct] = (f32x4){0.f, 0.f, 0.f, 0.f};
#pragma unroll
        for (int ct = 0; ct < 16; ++ct) {
            f16x8 b0 = Bf[(ct * 2 + 0) * 64 + l];
            f16x8 b1 = Bf[(ct * 2 + 1) * 64 + l];
            acc[ct] = mfma16(ah0, b0, acc[ct]);
            acc[ct] = mfma16(ah1, b1, acc[ct]);
            acc[ct] = mfma16(al0, b0, acc[ct]);
            acc[ct] = mfma16(al1, b1, acc[ct]);
        }
        float pa[4][3];
#pragma unroll
        for (int r = 0; r < 4; ++r) { pa[r][0] = 0.f; pa[r][1] = 0.f; pa[r][2] = 0.f; }
#pragma unroll
        for (int ct = 0; ct < 16; ++ct) {
            const int f = ct * 16 + lr;
            unsigned int u0 = BtP[f * 3 + 0], u1 = BtP[f * 3 + 1], u2 = BtP[f * 3 + 2];
            float bc0 = __uint_as_float(u0 << 16), bs0 = __uint_as_float(u0 & 0xffff0000u);
            float bc1 = __uint_as_float(u1 << 16), bs1 = __uint_as_float(u1 & 0xffff0000u);
            float bc2 = __uint_as_float(u2 << 16), bs2 = __uint_as_float(u2 & 0xffff0000u);
#pragma unroll
            for (int r = 0; r < 4; ++r) {
                float sn, cs;
                __sincosf(acc[ct][r], &sn, &cs);
                pa[r][0] = __builtin_fmaf(cs, bc0, __builtin_fmaf(sn, bs0, pa[r][0]));
                pa[r][1] = __builtin_fmaf(cs, bc1, __builtin_fmaf(sn, bs1, pa[r][1]));
                pa[r][2] = __builtin_fmaf(cs, bc2, __builtin_fmaf(sn, bs2, pa[r][2]));
            }
        }
#pragma unroll
        for (int r = 0; r < 4; ++r)
#pragma unroll
            for (int j = 0; j < 3; ++j) {
                pa[r][j] += __shfl_xor(pa[r][j], 1);
                pa[r][j] += __shfl_xor(pa[r][j], 2);
                pa[r][j] += __shfl_xor(pa[r][j], 4);
                pa[r][j] += __shfl_xor(pa[r][j], 8);
            }
        float q0 = 0.f, q1 = 0.f, q2 = 0.f;
#pragma unroll
        for (int r = 0; r < 4; ++r)
            if (lr == r) { q0 = pa[r][0]; q1 = pa[r][1]; q2 = pa[r][2]; }
        if (lr < 4) {
            const size_t n = (size_t)n0 + 4 * lh + lr;
            out[OFF_PRED + n * 3 + 0] = q0;
            out[OFF_PRED + n * 3 + 1] = q1;
            out[OFF_PRED + n * 3 + 2] = q2;
            float x0 = q0 * 0.0625f, x1 = q1 * 0.0625f, x2 = q2 * 0.0625f;
            float m = fmaxf(x0, fmaxf(x1, x2));
            float e0 = __expf(x0 - m), e1 = __expf(x1 - m), e2 = __expf(x2 - m);
            float inv = 1.0f / (e0 + e1 + e2);
            out[OFF_AW + n * 3 + 0] = e0 * inv;
            out[OFF_AW + n * 3 + 1] = e1 * inv;
            out[OFF_AW + n * 3 + 2] = e2 * inv;
        }
    }
}

extern "C" void kernel_launch(void* const* d_in, const int* in_sizes, int n_in,
                              void* d_out, int out_size, void* d_ws, size_t ws_size,
                              hipStream_t stream) {
    const float* Z = (const float*)d_in[0];
    const float* W = (const float*)d_in[1];
    const float* A = (const float*)d_in[2];
    float* out = (float*)d_out;
    float* ws = (float*)d_ws;

    (void)hipMemsetAsync(ws, 0, 512 * sizeof(float), stream);
    hipLaunchKernelGGL(k_pass1, dim3(GRID_BIG), dim3(256), 0, stream, Z, W, ws);
    hipLaunchKernelGGL(k_alpha, dim3(1), dim3(256), 0, stream, ws, A, ws, out);
    hipLaunchKernelGGL(k_pass2, dim3(GRID_BIG), dim3(256), 0, stream, Z, W, ws, out);
}